// Round 2
// baseline (529.429 us; speedup 1.0000x reference)
//
#include <hip/hip_runtime.h>

// SegmentedSmoothing: 5x5 clipped-window average where each pixel averages
// only same-class neighbors. Class = boundary band (within BW=10 of any edge)
// vs interior. Input/out: fp32 (4,16,720,1440).
//
// Single merged kernel: blocks [0, FAST_BLOCKS) run the pure-interior rolling
// box-sum path (8 outputs/thread/row, 24 rows/thread); blocks
// [FAST_BLOCKS, FAST_BLOCKS+EDGE_BLOCKS) run the masked general path over the
// thin complex band. The two regions are disjoint in output and read-only in
// input, so they run concurrently in one dispatch (previously two serialized
// launches).

#define HH 720
#define WW 1440
#define PLANE (HH * WW)   // 1,036,800
#define NPLANES 64        // 4*16

// ---- fast region geometry: i in [12,708), j in [12,1428) ----
// 8-wide groups: j0 = 12 + 8*g, g in [0,177). 29 chunks of 24 rows.
#define NG8 177
#define NCHUNK 29
#define CHUNK 24
#define NFAST (NG8 * NCHUNK)            // 5133 threads/plane
#define FAST_BLOCKS 21                  // ceil(5133/256)

// ---- edge region: rows {0..11, 708..719} full width (34560) +
//      rows 12..707 with j in {0..11, 1428..1439} (16704) = 51264 ----
#define NEDGE 51264
#define EDGE_BLOCKS 201                 // ceil(51264/256)

// clang native vector type — required by __builtin_nontemporal_store
// (HIP's float4 is a struct and is rejected).
typedef float v4f __attribute__((ext_vector_type(4)));

__device__ __forceinline__ void hsum8(const float* __restrict__ p, float h[8]) {
    // p points at element j0 (16B aligned). Need floats p[-2..9].
    const float2 l = *(const float2*)(p - 2);   // 8B aligned
    const float4 a = *(const float4*)(p);       // 16B aligned
    const float4 b = *(const float4*)(p + 4);   // 16B aligned
    const float2 r = *(const float2*)(p + 8);   // 16B aligned
    h[0] = l.x + l.y + a.x + a.y + a.z;
    h[1] = h[0] - l.x + a.w;
    h[2] = h[1] - l.y + b.x;
    h[3] = h[2] - a.x + b.y;
    h[4] = h[3] - a.y + b.z;
    h[5] = h[4] - a.z + b.w;
    h[6] = h[5] - a.w + r.x;
    h[7] = h[6] - b.x + r.y;
}

__global__ __launch_bounds__(256) void smooth_kernel(const float* __restrict__ x,
                                                     float* __restrict__ out) {
    const float* __restrict__ xp = x + (size_t)blockIdx.y * PLANE;
    float* __restrict__ op       = out + (size_t)blockIdx.y * PLANE;

    if (blockIdx.x < FAST_BLOCKS) {
        // ---------------- fast path: pure-interior region ----------------
        const int id = blockIdx.x * 256 + threadIdx.x;
        if (id >= NFAST) return;
        const int chunk = id / NG8;
        const int g     = id - chunk * NG8;
        const int j0    = 12 + 8 * g;
        const int row0  = 12 + chunk * CHUNK;

        float h[5][8];   // ring of 5 horizontal window-sums (all indices
                         // compile-time constant after full unroll)
        float V[8];      // running vertical sum of the 5 ring entries

        // prime rows row0-2 .. row0+1 into h[0..3]
#pragma unroll
        for (int t = 0; t < 4; ++t) {
            hsum8(xp + (row0 - 2 + t) * WW + j0, h[t]);
        }
#pragma unroll
        for (int c = 0; c < 8; ++c) V[c] = h[0][c] + h[1][c] + h[2][c] + h[3][c];

#pragma unroll
        for (int t = 0; t < CHUNK; ++t) {
            const int r = row0 + t;
            float* hn = h[(t + 4) % 5];           // row r+2 (incoming)
            const float* ho = h[t % 5];           // row r-2 (outgoing)
            hsum8(xp + (r + 2) * WW + j0, hn);

            const float s = 1.0f / 25.0f;
#pragma unroll
            for (int c = 0; c < 8; ++c) V[c] += hn[c];
            v4f v0, v1;
            v0.x = V[0] * s; v0.y = V[1] * s; v0.z = V[2] * s; v0.w = V[3] * s;
            v1.x = V[4] * s; v1.y = V[5] * s; v1.z = V[6] * s; v1.w = V[7] * s;
            // output is never re-read: stream past L2 to keep input resident
            __builtin_nontemporal_store(v0, (v4f*)(op + r * WW + j0));
            __builtin_nontemporal_store(v1, (v4f*)(op + r * WW + j0 + 4));
#pragma unroll
            for (int c = 0; c < 8; ++c) V[c] -= ho[c];
        }
        return;
    }

    // ---------------- edge path: complex band ----------------
    const int p = (blockIdx.x - FAST_BLOCKS) * 256 + threadIdx.x;
    if (p >= NEDGE) return;
    int i, j;
    if (p < 34560) {
        i = p / 1440;
        j = p - i * 1440;
        if (i >= 12) i += 696;   // 12..23 -> 708..719
    } else {
        const int q  = p - 34560;
        const int qi = q / 24;
        const int rr = q - qi * 24;
        i = 12 + qi;
        j = (rr < 12) ? rr : rr + 1416;  // 1428..1439
    }

    const bool cb = (i < 10) | (i >= 710) | (j < 10) | (j >= 1430);

    float s = 0.0f, cnt = 0.0f;
#pragma unroll
    for (int di = -2; di <= 2; ++di) {
#pragma unroll
        for (int dj = -2; dj <= 2; ++dj) {
            const int ni = i + di, nj = j + dj;
            const bool inb = ((unsigned)ni < (unsigned)HH) & ((unsigned)nj < (unsigned)WW);
            const bool nb  = (ni < 10) | (ni >= 710) | (nj < 10) | (nj >= 1430);
            const int ci = min(max(ni, 0), HH - 1);
            const int cj = min(max(nj, 0), WW - 1);
            const float v = xp[ci * WW + cj];
            const float w = (inb && (nb == cb)) ? 1.0f : 0.0f;
            s += w * v;
            cnt += w;
        }
    }
    op[i * WW + j] = s / cnt;
}

extern "C" void kernel_launch(void* const* d_in, const int* in_sizes, int n_in,
                              void* d_out, int out_size, void* d_ws, size_t ws_size,
                              hipStream_t stream) {
    const float* x = (const float*)d_in[0];
    float* out = (float*)d_out;

    dim3 grid(FAST_BLOCKS + EDGE_BLOCKS, NPLANES);
    hipLaunchKernelGGL(smooth_kernel, grid, dim3(256), 0, stream, x, out);
}

// Round 3
// 463.263 us; speedup vs baseline: 1.1428x; 1.1428x over previous
//
#include <hip/hip_runtime.h>

// SegmentedSmoothing: 5x5 clipped-window average where each pixel averages
// only same-class neighbors. Class = boundary band (within BW=10 of any edge)
// vs interior. Input/out: fp32 (4,16,720,1440).
//
// Single merged kernel: blocks [0, FAST_BLOCKS) run the pure-interior rolling
// box-sum path (8 outputs/thread/row, 8 rows/thread); blocks
// [FAST_BLOCKS, FAST_BLOCKS+EDGE_BLOCKS) run the masked general path over the
// thin complex band.
//
// Round-2 notes:
//  - NT stores removed: they caused 1.5x HBM write amplification (399 MB vs
//    265 MB compulsory) by defeating L2 write-combining.
//  - CHUNK 24 -> 8: fast path was latency-bound (VALUBusy 12.5%, occ 30%,
//    only 5.1K waves device-wide). 15.4K waves now; halo re-reads are L2 hits.
//  - VGPR must stay <= 64 (occupancy halves at the 64-VGPR step); no explicit
//    prefetch staging for that reason.

#define HH 720
#define WW 1440
#define PLANE (HH * WW)   // 1,036,800
#define NPLANES 64        // 4*16

// ---- fast region geometry: i in [12,708), j in [12,1428) ----
// 8-wide groups: j0 = 12 + 8*g, g in [0,177). 87 chunks of 8 rows.
#define NG8 177
#define NCHUNK 87
#define CHUNK 8
#define NFAST (NG8 * NCHUNK)            // 15399 threads/plane
#define FAST_BLOCKS 61                  // ceil(15399/256)

// ---- edge region: rows {0..11, 708..719} full width (34560) +
//      rows 12..707 with j in {0..11, 1428..1439} (16704) = 51264 ----
#define NEDGE 51264
#define EDGE_BLOCKS 201                 // ceil(51264/256)

typedef float v4f __attribute__((ext_vector_type(4)));

__device__ __forceinline__ void hsum8(const float* __restrict__ p, float h[8]) {
    // p points at element j0 (16B aligned). Need floats p[-2..9].
    const float2 l = *(const float2*)(p - 2);   // 8B aligned
    const float4 a = *(const float4*)(p);       // 16B aligned
    const float4 b = *(const float4*)(p + 4);   // 16B aligned
    const float2 r = *(const float2*)(p + 8);   // 16B aligned
    h[0] = l.x + l.y + a.x + a.y + a.z;
    h[1] = h[0] - l.x + a.w;
    h[2] = h[1] - l.y + b.x;
    h[3] = h[2] - a.x + b.y;
    h[4] = h[3] - a.y + b.z;
    h[5] = h[4] - a.z + b.w;
    h[6] = h[5] - a.w + r.x;
    h[7] = h[6] - b.x + r.y;
}

__global__ __launch_bounds__(256) void smooth_kernel(const float* __restrict__ x,
                                                     float* __restrict__ out) {
    const float* __restrict__ xp = x + (size_t)blockIdx.y * PLANE;
    float* __restrict__ op       = out + (size_t)blockIdx.y * PLANE;

    if (blockIdx.x < FAST_BLOCKS) {
        // ---------------- fast path: pure-interior region ----------------
        const int id = blockIdx.x * 256 + threadIdx.x;
        if (id >= NFAST) return;
        const int chunk = id / NG8;
        const int g     = id - chunk * NG8;
        const int j0    = 12 + 8 * g;
        const int row0  = 12 + chunk * CHUNK;

        float h[5][8];   // ring of 5 horizontal window-sums (all indices
                         // compile-time constant after full unroll)
        float V[8];      // running vertical sum of the 5 ring entries

        // prime rows row0-2 .. row0+1 into h[0..3]
#pragma unroll
        for (int t = 0; t < 4; ++t) {
            hsum8(xp + (row0 - 2 + t) * WW + j0, h[t]);
        }
#pragma unroll
        for (int c = 0; c < 8; ++c) V[c] = h[0][c] + h[1][c] + h[2][c] + h[3][c];

#pragma unroll
        for (int t = 0; t < CHUNK; ++t) {
            const int r = row0 + t;
            float* hn = h[(t + 4) % 5];           // row r+2 (incoming)
            const float* ho = h[t % 5];           // row r-2 (outgoing)
            hsum8(xp + (r + 2) * WW + j0, hn);

            const float s = 1.0f / 25.0f;
#pragma unroll
            for (int c = 0; c < 8; ++c) V[c] += hn[c];
            v4f v0, v1;
            v0.x = V[0] * s; v0.y = V[1] * s; v0.z = V[2] * s; v0.w = V[3] * s;
            v1.x = V[4] * s; v1.y = V[5] * s; v1.z = V[6] * s; v1.w = V[7] * s;
            *(v4f*)(op + r * WW + j0) = v0;
            *(v4f*)(op + r * WW + j0 + 4) = v1;
#pragma unroll
            for (int c = 0; c < 8; ++c) V[c] -= ho[c];
        }
        return;
    }

    // ---------------- edge path: complex band ----------------
    const int p = (blockIdx.x - FAST_BLOCKS) * 256 + threadIdx.x;
    if (p >= NEDGE) return;
    int i, j;
    if (p < 34560) {
        i = p / 1440;
        j = p - i * 1440;
        if (i >= 12) i += 696;   // 12..23 -> 708..719
    } else {
        const int q  = p - 34560;
        const int qi = q / 24;
        const int rr = q - qi * 24;
        i = 12 + qi;
        j = (rr < 12) ? rr : rr + 1416;  // 1428..1439
    }

    const bool cb = (i < 10) | (i >= 710) | (j < 10) | (j >= 1430);

    float s = 0.0f, cnt = 0.0f;
#pragma unroll
    for (int di = -2; di <= 2; ++di) {
#pragma unroll
        for (int dj = -2; dj <= 2; ++dj) {
            const int ni = i + di, nj = j + dj;
            const bool inb = ((unsigned)ni < (unsigned)HH) & ((unsigned)nj < (unsigned)WW);
            const bool nb  = (ni < 10) | (ni >= 710) | (nj < 10) | (nj >= 1430);
            const int ci = min(max(ni, 0), HH - 1);
            const int cj = min(max(nj, 0), WW - 1);
            const float v = xp[ci * WW + cj];
            const float w = (inb && (nb == cb)) ? 1.0f : 0.0f;
            s += w * v;
            cnt += w;
        }
    }
    op[i * WW + j] = s / cnt;
}

extern "C" void kernel_launch(void* const* d_in, const int* in_sizes, int n_in,
                              void* d_out, int out_size, void* d_ws, size_t ws_size,
                              hipStream_t stream) {
    const float* x = (const float*)d_in[0];
    float* out = (float*)d_out;

    dim3 grid(FAST_BLOCKS + EDGE_BLOCKS, NPLANES);
    hipLaunchKernelGGL(smooth_kernel, grid, dim3(256), 0, stream, x, out);
}